// Round 3
// baseline (616.517 us; speedup 1.0000x reference)
//
#include <hip/hip_runtime.h>
#include <math.h>

#define NROWS 4096
#define NCOLS 32000
#define NC4   8000   // NCOLS / 4

// Single fused kernel:
//   block 0        : reaction-time transform (histogram order-statistic
//                    selection, no sort) -> ws_rt. Dispatched FIRST so it
//                    hides completely under the CE blocks.
//   blocks 1..4096 : one row each -> CE + argmax, single memory pass,
//                    branchless, register-chunked (2 chunks x 64 floats/thr).
//   last block to finish (ticket == NROWS): deterministic fixed-order
//                    final reduction -> out[0].
__global__ __launch_bounds__(256, 4) void rt_fused_kernel(
    const float* __restrict__ logits,
    const int*   __restrict__ target,
    const float* __restrict__ rt_in,
    float* __restrict__ ws_rt,
    float* __restrict__ ws_ce,
    float* __restrict__ ws_flag,
    unsigned int* __restrict__ counter,
    float* __restrict__ out)
{
    __shared__ int   hist[4096];
    __shared__ float cand[4][64];
    __shared__ int   ccnt[4];
    __shared__ int   tbin[4], lrank[4];
    __shared__ float quart[4];
    __shared__ int   wsum[4];
    __shared__ float fred[16];
    __shared__ float sm4[4], ss4[4];
    __shared__ int   si4[4];
    __shared__ unsigned int tick_s;

    const int t    = threadIdx.x;
    const int lane = t & 63, wv = t >> 6;

    if (blockIdx.x == 0) {
        // ---------- reaction-time transform ----------
        // 1) value histogram (rt uniform in [0,1): bin = floor(x*4096))
        for (int i = t; i < 4096; i += 256) hist[i] = 0;
        __syncthreads();
        for (int i = t; i < 4096; i += 256) {
            float x = rt_in[i];
            int b = (int)(x * 4096.0f);
            b = b < 0 ? 0 : (b > 4095 ? 4095 : b);
            atomicAdd(&hist[b], 1);
        }
        __syncthreads();
        // 2) inclusive scan over the 4096 bins (16 bins/thread + wave scan)
        int base = t * 16;
        int run = 0, loc[16];
        #pragma unroll
        for (int i = 0; i < 16; ++i) { run += hist[base + i]; loc[i] = run; }
        int v = run;
        for (int off = 1; off < 64; off <<= 1) {
            int o = __shfl_up(v, off);
            if (lane >= off) v += o;
        }
        if (lane == 63) wsum[wv] = v;
        __syncthreads();
        int woff = 0;
        for (int w = 0; w < wv; ++w) woff += wsum[w];
        int excl = v - run + woff;          // exclusive prefix for this chunk
        #pragma unroll
        for (int i = 0; i < 16; ++i) hist[base + i] = loc[i] + excl; // inclusive
        if (t < 4) ccnt[t] = 0;
        __syncthreads();
        // 3) locate bins holding ranks 1023,1024,3071,3072 (0-based)
        if (t < 4) {
            const int ranks[4] = {1023, 1024, 3071, 3072};
            int r = ranks[t];
            int lo = 0, hi = 4095;
            while (lo < hi) { int mid = (lo + hi) >> 1; if (hist[mid] >= r + 1) hi = mid; else lo = mid + 1; }
            tbin[t]  = lo;
            lrank[t] = r - (lo ? hist[lo - 1] : 0);
        }
        __syncthreads();
        // 4) collect candidates in those bins
        for (int i = t; i < 4096; i += 256) {
            float x = rt_in[i];
            int b = (int)(x * 4096.0f);
            b = b < 0 ? 0 : (b > 4095 ? 4095 : b);
            #pragma unroll
            for (int k = 0; k < 4; ++k)
                if (b == tbin[k]) {
                    int sl = atomicAdd(&ccnt[k], 1);
                    if (sl < 64) cand[k][sl] = x;
                }
        }
        __syncthreads();
        // 5) lr-th smallest within bin via O(c^2) counting (c ~ Poisson(1))
        if (t < 4) {
            int n  = ccnt[t] < 64 ? ccnt[t] : 64;
            int lr = lrank[t];
            float res = 0.0f;
            for (int i = 0; i < n; ++i) {
                float ci = cand[t][i];
                int lt = 0, le = 0;
                for (int j = 0; j < n; ++j) {
                    float cj = cand[t][j];
                    lt += (cj < ci); le += (cj <= ci);
                }
                if (lt <= lr && lr < le) res = ci;
            }
            quart[t] = res;
        }
        __syncthreads();
        // jnp.quantile linear interp: 0.25*4095=1023.75, 0.75*4095=3071.25
        float lower = quart[0] * 0.25f + quart[1] * 0.75f;
        float upper = quart[2] * 0.75f + quart[3] * 0.25f;
        // 6) clamp tails, interior min/max, normalize
        float mn = 100.0f, mx = -100.0f;   // reference sentinels
        float w16[16];
        #pragma unroll
        for (int c = 0; c < 16; ++c) {
            int i = t + c * 256;
            float x = rt_in[i];
            float w = x < lower ? 0.0f : (x > upper ? 1.0f : x);
            w16[c] = w;
            if (w != 0.0f && w != 1.0f) { mn = fminf(mn, w); mx = fmaxf(mx, w); }
        }
        for (int off = 32; off; off >>= 1) {
            mn = fminf(mn, __shfl_xor(mn, off));
            mx = fmaxf(mx, __shfl_xor(mx, off));
        }
        if (lane == 0) { fred[wv] = mn; fred[8 + wv] = mx; }
        __syncthreads();
        mn = fminf(fminf(fred[0], fred[1]), fminf(fred[2], fred[3]));
        mx = fmaxf(fmaxf(fred[8], fred[9]), fmaxf(fred[10], fred[11]));
        #pragma unroll
        for (int c = 0; c < 16; ++c) {
            int i = t + c * 256;
            float w = w16[c];
            bool interior = (w != 0.0f) && (w != 1.0f);
            ws_rt[i] = interior ? (w - mn) / mx : w;   // reference divides by max
        }
    } else {
        // ---------- per-row cross-entropy + argmax, branchless ----------
        const int row = blockIdx.x - 1;
        const float*  rp  = logits + (size_t)row * NCOLS;
        const float4* rp4 = (const float4*)rp;

        float m = -3.0e38f, sum = 0.0f;
        int idx = 0x7fffffff;

        #pragma unroll 1
        for (int ch = 0; ch < 2; ++ch) {
            // batched, unconditional (index-clamped) loads: 16 float4/thread
            float4 v[16];
            #pragma unroll
            for (int c = 0; c < 16; ++c) {
                int p = t + (ch * 16 + c) * 256;
                int pc = p < NC4 ? p : NC4 - 1;
                v[c] = rp4[pc];
                if (ch == 1 && c == 15) {      // only place p can exceed NC4
                    if (p >= NC4) { v[c].x = -3.0e38f; v[c].y = -3.0e38f; v[c].z = -3.0e38f; v[c].w = -3.0e38f; }
                }
            }
            // chunk max + first-index argmax (ascending order, strict >)
            float cm = -3.0e38f; int ci = 0x7fffffff;
            #pragma unroll
            for (int c = 0; c < 16; ++c) {
                int p = t + (ch * 16 + c) * 256;
                float xs[4] = {v[c].x, v[c].y, v[c].z, v[c].w};
                #pragma unroll
                for (int q = 0; q < 4; ++q) {
                    bool g = xs[q] > cm;
                    cm = g ? xs[q] : cm;
                    ci = g ? p * 4 + q : ci;
                }
            }
            float nm = fmaxf(m, cm);
            sum *= __expf(m - nm);             // rescale old partial sum
            if (cm > m) idx = ci;              // tie -> keep earlier chunk
            m = nm;
            // independent exp's, 4 partial accumulators (ILP)
            float s0 = 0.0f, s1 = 0.0f, s2 = 0.0f, s3 = 0.0f;
            #pragma unroll
            for (int c = 0; c < 16; ++c) {
                s0 += __expf(v[c].x - nm);
                s1 += __expf(v[c].y - nm);
                s2 += __expf(v[c].z - nm);
                s3 += __expf(v[c].w - nm);
            }
            sum += (s0 + s1) + (s2 + s3);
        }

        // wave combine of (m, sum, idx); tie -> smaller index
        for (int off = 32; off; off >>= 1) {
            float om = __shfl_xor(m, off);
            float os = __shfl_xor(sum, off);
            int   oi = __shfl_xor(idx, off);
            float nm = fmaxf(m, om);
            float ns = sum * __expf(m - nm) + os * __expf(om - nm);
            if (om > m || (om == m && oi < idx)) idx = oi;
            m = nm; sum = ns;
        }
        if (lane == 0) { sm4[wv] = m; ss4[wv] = sum; si4[wv] = idx; }
        __syncthreads();
        if (t == 0) {
            float M = sm4[0], S = ss4[0];
            int   I = si4[0];
            for (int w2 = 1; w2 < 4; ++w2) {
                float om = sm4[w2], os = ss4[w2];
                int   oi = si4[w2];
                float nmm = fmaxf(M, om);
                S = S * __expf(M - nmm) + os * __expf(om - nmm);
                if (om > M || (om == M && oi < I)) I = oi;
                M = nmm;
            }
            int tg = target[row];
            float xt = rp[tg];
            ws_ce[row]   = M + logf(S) - xt;          // -log_softmax[target]
            ws_flag[row] = (I != tg) ? 1.0f : 0.0f;   // mispredicted?
        }
    }

    // ---------- last-block-ticket final reduction ----------
    __threadfence();               // release: make this block's ws writes device-visible
    __syncthreads();               // order all threads' fences before t0's atomic
    if (t == 0) tick_s = atomicAdd(counter, 1u);
    __syncthreads();
    if (tick_s == NROWS) {         // last of NROWS+1 blocks
        __threadfence();           // acquire: see all other blocks' ws writes
        volatile const float* vrt = ws_rt;
        volatile const float* vce = ws_ce;
        volatile const float* vfl = ws_flag;
        float a = 0.0f;
        #pragma unroll
        for (int c = 0; c < 16; ++c) {
            int i = t + c * 256;
            a += vce[i] + vfl[i] * vrt[i];
        }
        float* fs = (float*)hist;  // reuse LDS (safe: all prior uses sync'd)
        __syncthreads();
        fs[t] = a;
        __syncthreads();
        for (int off = 128; off; off >>= 1) {
            if (t < off) fs[t] += fs[t + off];
            __syncthreads();
        }
        if (t == 0) out[0] = fs[0] * (1.0f / 4096.0f);
    }
}

extern "C" void kernel_launch(void* const* d_in, const int* in_sizes, int n_in,
                              void* d_out, int out_size, void* d_ws, size_t ws_size,
                              hipStream_t stream) {
    const float* logits = (const float*)d_in[0];
    const int*   target = (const int*)d_in[1];
    const float* rt     = (const float*)d_in[2];

    float* ws_rt   = (float*)d_ws;
    float* ws_ce   = ws_rt + NROWS;
    float* ws_flag = ws_ce + NROWS;
    unsigned int* counter = (unsigned int*)(ws_flag + NROWS);

    hipMemsetAsync(counter, 0, sizeof(unsigned int), stream);
    rt_fused_kernel<<<NROWS + 1, 256, 0, stream>>>(logits, target, rt,
                                                   ws_rt, ws_ce, ws_flag,
                                                   counter, (float*)d_out);
}

// Round 4
// 98.091 us; speedup vs baseline: 6.2852x; 6.2852x over previous
//
#include <hip/hip_runtime.h>
#include <math.h>

#define NROWS 4096
#define NCOLS 32000
#define NC4   8000   // NCOLS / 4

// Block 0:        reaction-time transform via histogram order-statistic
//                 selection (no sort) -> dispatched FIRST, hides under CE.
// Blocks 1..4096: one row each -> CE + argmax, single memory pass,
//                 branchless, register-chunked (2 chunks x 64 floats/thread).
// (Reduction kept in a separate kernel: round-3 showed fusing it into this
//  kernel wrecks regalloc -> VGPR 52 -> serialized loads -> 6x slower.)
__global__ __launch_bounds__(256, 4) void rt_main_kernel(
    const float* __restrict__ logits,
    const int*   __restrict__ target,
    const float* __restrict__ rt_in,
    float* __restrict__ ws_rt,
    float* __restrict__ ws_ce,
    float* __restrict__ ws_flag)
{
    __shared__ int   hist[4096];
    __shared__ float cand[4][64];
    __shared__ int   ccnt[4];
    __shared__ int   tbin[4], lrank[4];
    __shared__ float quart[4];
    __shared__ int   wsum[4];
    __shared__ float fred[16];
    __shared__ float sm[4], ss[4];
    __shared__ int   si4[4];

    const int t    = threadIdx.x;
    const int lane = t & 63, wv = t >> 6;

    if (blockIdx.x == 0) {
        // ---------- reaction-time transform ----------
        // 1) value histogram (rt uniform in [0,1): bin = floor(x*4096))
        for (int i = t; i < 4096; i += 256) hist[i] = 0;
        __syncthreads();
        for (int i = t; i < 4096; i += 256) {
            float x = rt_in[i];
            int b = (int)(x * 4096.0f);
            b = b < 0 ? 0 : (b > 4095 ? 4095 : b);
            atomicAdd(&hist[b], 1);
        }
        __syncthreads();
        // 2) inclusive scan over the 4096 bins (16 bins/thread + wave scan)
        int base = t * 16;
        int run = 0, loc[16];
        #pragma unroll
        for (int i = 0; i < 16; ++i) { run += hist[base + i]; loc[i] = run; }
        int v = run;
        for (int off = 1; off < 64; off <<= 1) {
            int o = __shfl_up(v, off);
            if (lane >= off) v += o;
        }
        if (lane == 63) wsum[wv] = v;
        __syncthreads();
        int woff = 0;
        for (int w = 0; w < wv; ++w) woff += wsum[w];
        int excl = v - run + woff;          // exclusive prefix for this chunk
        #pragma unroll
        for (int i = 0; i < 16; ++i) hist[base + i] = loc[i] + excl;   // inclusive
        if (t < 4) ccnt[t] = 0;
        __syncthreads();
        // 3) locate bins holding ranks 1023,1024,3071,3072 (0-based)
        if (t < 4) {
            const int ranks[4] = {1023, 1024, 3071, 3072};
            int r = ranks[t];
            int lo = 0, hi = 4095;
            while (lo < hi) { int mid = (lo + hi) >> 1; if (hist[mid] >= r + 1) hi = mid; else lo = mid + 1; }
            tbin[t]  = lo;
            lrank[t] = r - (lo ? hist[lo - 1] : 0);
        }
        __syncthreads();
        // 4) collect candidates in those bins
        for (int i = t; i < 4096; i += 256) {
            float x = rt_in[i];
            int b = (int)(x * 4096.0f);
            b = b < 0 ? 0 : (b > 4095 ? 4095 : b);
            #pragma unroll
            for (int k = 0; k < 4; ++k)
                if (b == tbin[k]) {
                    int sl = atomicAdd(&ccnt[k], 1);
                    if (sl < 64) cand[k][sl] = x;
                }
        }
        __syncthreads();
        // 5) lr-th smallest within bin via O(c^2) counting (c ~ Poisson(1))
        if (t < 4) {
            int n  = ccnt[t] < 64 ? ccnt[t] : 64;
            int lr = lrank[t];
            float res = 0.0f;
            for (int i = 0; i < n; ++i) {
                float ci = cand[t][i];
                int lt = 0, le = 0;
                for (int j = 0; j < n; ++j) {
                    float cj = cand[t][j];
                    lt += (cj < ci); le += (cj <= ci);
                }
                if (lt <= lr && lr < le) res = ci;
            }
            quart[t] = res;
        }
        __syncthreads();
        // jnp.quantile linear interp: 0.25*4095=1023.75, 0.75*4095=3071.25
        float lower = quart[0] * 0.25f + quart[1] * 0.75f;
        float upper = quart[2] * 0.75f + quart[3] * 0.25f;
        // 6) clamp tails, interior min/max, normalize
        float mn = 100.0f, mx = -100.0f;   // reference sentinels
        float w16[16];
        #pragma unroll
        for (int c = 0; c < 16; ++c) {
            int i = t + c * 256;
            float x = rt_in[i];
            float w = x < lower ? 0.0f : (x > upper ? 1.0f : x);
            w16[c] = w;
            if (w != 0.0f && w != 1.0f) { mn = fminf(mn, w); mx = fmaxf(mx, w); }
        }
        for (int off = 32; off; off >>= 1) {
            mn = fminf(mn, __shfl_xor(mn, off));
            mx = fmaxf(mx, __shfl_xor(mx, off));
        }
        if (lane == 0) { fred[wv] = mn; fred[8 + wv] = mx; }
        __syncthreads();
        mn = fminf(fminf(fred[0], fred[1]), fminf(fred[2], fred[3]));
        mx = fmaxf(fmaxf(fred[8], fred[9]), fmaxf(fred[10], fred[11]));
        #pragma unroll
        for (int c = 0; c < 16; ++c) {
            int i = t + c * 256;
            float w = w16[c];
            bool interior = (w != 0.0f) && (w != 1.0f);
            ws_rt[i] = interior ? (w - mn) / mx : w;   // reference divides by max
        }
        return;
    }

    // ---------- per-row cross-entropy + argmax, branchless ----------
    const int row = blockIdx.x - 1;
    const float*  rp  = logits + (size_t)row * NCOLS;
    const float4* rp4 = (const float4*)rp;

    float m = -3.0e38f, sum = 0.0f;
    int idx = 0x7fffffff;

    #pragma unroll 1
    for (int ch = 0; ch < 2; ++ch) {
        // batched, unconditional (index-clamped) loads: 16 float4 per thread
        float4 v[16];
        #pragma unroll
        for (int c = 0; c < 16; ++c) {
            int p = t + (ch * 16 + c) * 256;
            int pc = p < NC4 ? p : NC4 - 1;
            v[c] = rp4[pc];
            if (ch == 1 && c == 15) {      // only place p can exceed NC4
                if (p >= NC4) { v[c].x = -3.0e38f; v[c].y = -3.0e38f; v[c].z = -3.0e38f; v[c].w = -3.0e38f; }
            }
        }
        // chunk max + first-index argmax (ascending order, strict >)
        float cm = -3.0e38f; int ci = 0x7fffffff;
        #pragma unroll
        for (int c = 0; c < 16; ++c) {
            int p = t + (ch * 16 + c) * 256;
            float xs[4] = {v[c].x, v[c].y, v[c].z, v[c].w};
            #pragma unroll
            for (int q = 0; q < 4; ++q) {
                bool g = xs[q] > cm;
                cm = g ? xs[q] : cm;
                ci = g ? p * 4 + q : ci;
            }
        }
        float nm = fmaxf(m, cm);
        sum *= __expf(m - nm);             // rescale old partial sum
        if (cm > m) idx = ci;              // tie -> keep earlier chunk's index
        m = nm;
        // independent exp's, 4 partial accumulators (ILP)
        float s0 = 0.0f, s1 = 0.0f, s2 = 0.0f, s3 = 0.0f;
        #pragma unroll
        for (int c = 0; c < 16; ++c) {
            s0 += __expf(v[c].x - nm);
            s1 += __expf(v[c].y - nm);
            s2 += __expf(v[c].z - nm);
            s3 += __expf(v[c].w - nm);
        }
        sum += (s0 + s1) + (s2 + s3);
    }

    // wave combine of (m, sum, idx); tie -> smaller index
    for (int off = 32; off; off >>= 1) {
        float om = __shfl_xor(m, off);
        float os = __shfl_xor(sum, off);
        int   oi = __shfl_xor(idx, off);
        float nm = fmaxf(m, om);
        float ns = sum * __expf(m - nm) + os * __expf(om - nm);
        if (om > m || (om == m && oi < idx)) idx = oi;
        m = nm; sum = ns;
    }
    if (lane == 0) { sm[wv] = m; ss[wv] = sum; si4[wv] = idx; }
    __syncthreads();
    if (t == 0) {
        float M = sm[0], S = ss[0];
        int   I = si4[0];
        for (int w2 = 1; w2 < 4; ++w2) {
            float om = sm[w2], os = ss[w2];
            int   oi = si4[w2];
            float nm = fmaxf(M, om);
            S = S * __expf(M - nm) + os * __expf(om - nm);
            if (om > M || (om == M && oi < I)) I = oi;
            M = nm;
        }
        int tg = target[row];
        float xt = rp[tg];
        ws_ce[row]   = M + logf(S) - xt;          // -log_softmax[target]
        ws_flag[row] = (I != tg) ? 1.0f : 0.0f;   // mispredicted?
    }
}

// Deterministic final mean: ce + wrong*rt_transformed, fixed tree order.
__global__ __launch_bounds__(1024) void rt_reduce_kernel(
    const float* __restrict__ ws_rt,
    const float* __restrict__ ws_ce,
    const float* __restrict__ ws_flag,
    float* __restrict__ out)
{
    __shared__ float s[1024];
    const int t = threadIdx.x;
    float a = 0.0f;
    #pragma unroll
    for (int c = 0; c < 4; ++c) {
        int i = t + c * 1024;
        a += ws_ce[i] + ws_flag[i] * ws_rt[i];
    }
    s[t] = a;
    __syncthreads();
    for (int off = 512; off; off >>= 1) {
        if (t < off) s[t] += s[t + off];
        __syncthreads();
    }
    if (t == 0) out[0] = s[0] * (1.0f / 4096.0f);
}

extern "C" void kernel_launch(void* const* d_in, const int* in_sizes, int n_in,
                              void* d_out, int out_size, void* d_ws, size_t ws_size,
                              hipStream_t stream) {
    const float* logits = (const float*)d_in[0];
    const int*   target = (const int*)d_in[1];
    const float* rt     = (const float*)d_in[2];

    float* ws_rt   = (float*)d_ws;
    float* ws_ce   = ws_rt + NROWS;
    float* ws_flag = ws_ce + NROWS;

    rt_main_kernel<<<NROWS + 1, 256, 0, stream>>>(logits, target, rt,
                                                  ws_rt, ws_ce, ws_flag);
    rt_reduce_kernel<<<1, 1024, 0, stream>>>(ws_rt, ws_ce, ws_flag, (float*)d_out);
}